// Round 8
// baseline (266.610 us; speedup 1.0000x reference)
//
#include <hip/hip_runtime.h>

#define NB 512
#define NC 512
#define HD 128
typedef float2 f2;
typedef float4 f4;

// 8-slot k-split matmul over 4 source rows (stride SSTR) from LDS; W from L2.
// Each f2 weight load feeds 8 FMAs (4 rows x 2 cols); loads independent.
#define ACC8S(SB, SSTR, WP, KQ) { const f2* W2_ = (const f2*)(WP); const float* S_ = (SB); \
  _Pragma("unroll 8") for (int kk_ = 0; kk_ < (KQ); ++kk_) { \
    int k_ = slot * (KQ) + kk_; \
    f2 w_ = W2_[k_ * 64 + cg]; \
    float s0_ = S_[k_], s1_ = S_[(SSTR) + k_], s2_ = S_[2*(SSTR) + k_], s3_ = S_[3*(SSTR) + k_]; \
    a0 = fmaf(s0_, w_.x, a0); a1 = fmaf(s0_, w_.y, a1); \
    a2 = fmaf(s1_, w_.x, a2); a3 = fmaf(s1_, w_.y, a3); \
    a4 = fmaf(s2_, w_.x, a4); a5 = fmaf(s2_, w_.y, a5); \
    a6 = fmaf(s3_, w_.x, a6); a7 = fmaf(s3_, w_.y, a7); } }
#define ZACC() { a0=a1=a2=a3=a4=a5=a6=a7=0.f; }
#define WRPART() { float* P_ = part + slot * 512; \
  *(f2*)&P_[c0]     = make_float2(a0, a1); *(f2*)&P_[128 + c0] = make_float2(a2, a3); \
  *(f2*)&P_[256 + c0] = make_float2(a4, a5); *(f2*)&P_[384 + c0] = make_float2(a6, a7); }
#define PSUM(r_, cc_) (part[(r_)*128+(cc_)] + part[512+(r_)*128+(cc_)] + \
  part[1024+(r_)*128+(cc_)] + part[1536+(r_)*128+(cc_)] + part[2048+(r_)*128+(cc_)] + \
  part[2560+(r_)*128+(cc_)] + part[3072+(r_)*128+(cc_)] + part[3584+(r_)*128+(cc_)])

// grid barrier: monotonic counter (memset to 0 per launch), agent scope.
__device__ __forceinline__ void gbar(unsigned* bar, unsigned target) {
  __syncthreads();
  if (threadIdx.x == 0) {
    __threadfence();
    __hip_atomic_fetch_add(bar, 1u, __ATOMIC_RELEASE, __HIP_MEMORY_SCOPE_AGENT);
    while (__hip_atomic_load(bar, __ATOMIC_ACQUIRE, __HIP_MEMORY_SCOPE_AGENT) < target)
      __builtin_amdgcn_s_sleep(2);
  }
  __syncthreads();
  __threadfence();
}

// One GNN layer for this block's 4 node rows. um = my-side u/v rows (LDS),
// other = opposite side's full endpoint array (global). Updates xa,um in LDS;
// writes my new endpoint rows to mine_out (if non-null) for the other side.
__device__ __forceinline__ void phaseT(
    int tid, int cg, int slot, int c0, bool bird, int rside,
    float* xa, float* um, float* part, float* rsp, float* rs, float* ag,
    float* h1, float* xo, const float* other,
    const float* ew2l, const float* eb2l, const float* nw1l, const float* nb1l,
    const float* nw2l, const float* nb2l, const float* ew1n, const float* eb1n,
    float* mine_out) {
  float a0, a1, a2, a3, a4, a5, a6, a7;
  {  // relu-sum: 16 slots = 4 rows x 4 j-quarters, f4 streams from L2
    const int s16 = tid >> 5, cg32 = tid & 31;
    const int row = s16 & 3, jq = s16 >> 2;
    f4 base = *(const f4*)&um[row * HD + 4 * cg32];
    const f4* O4 = (const f4*)other;
    f4 acc = make_float4(0.f, 0.f, 0.f, 0.f);
#pragma unroll 8
    for (int j = jq * 128; j < jq * 128 + 128; ++j) {
      f4 o = O4[j * 32 + cg32];
      acc.x += fmaxf(base.x + o.x, 0.f);
      acc.y += fmaxf(base.y + o.y, 0.f);
      acc.z += fmaxf(base.z + o.z, 0.f);
      acc.w += fmaxf(base.w + o.w, 0.f);
    }
    *(f4*)&rsp[s16 * HD + 4 * cg32] = acc;
  }
  __syncthreads();
  { int r = tid >> 7, cc = tid & 127;
    rs[r * HD + cc] = rsp[r * HD + cc] + rsp[(4 + r) * HD + cc] +
                      rsp[(8 + r) * HD + cc] + rsp[(12 + r) * HD + cc]; }
  __syncthreads();
  ZACC(); ACC8S(rs, HD, ew2l, 16); WRPART();                 // aggr
  __syncthreads();
  { int r = tid >> 7, cc = tid & 127;
    ag[r * HD + cc] = PSUM(r, cc) + 512.f * eb2l[cc]; }
  __syncthreads();
  ZACC(); ACC8S(xa, HD, nw1l, 16); ACC8S(ag, HD, nw1l + HD * HD, 16);  // mlp1
  WRPART();
  __syncthreads();
  { int r = tid >> 7, cc = tid & 127;
    h1[r * HD + cc] = fmaxf(PSUM(r, cc) + nb1l[cc], 0.f); }
  __syncthreads();
  ZACC(); ACC8S(h1, HD, nw2l, 16); WRPART();                 // mlp2
  __syncthreads();
  { int r = tid >> 7, cc = tid & 127;
    xo[r * HD + cc] = PSUM(r, cc) + nb2l[cc]; }
  __syncthreads();
  ZACC(); ACC8S(xo, HD, bird ? ew1n : ew1n + HD * HD, 16); WRPART();  // next u/v
  __syncthreads();
  { int r = tid >> 7, cc = tid & 127;
    float uval = PSUM(r, cc) + (bird ? eb1n[cc] : 0.f);
    um[r * HD + cc] = uval;
    if (mine_out) mine_out[(rside + r) * HD + cc] = uval;
    xa[r * HD + cc] = xo[r * HD + cc]; }
}

__global__ __launch_bounds__(512) void mega(
    const float* __restrict__ probs, const float* __restrict__ npw,
    const float* __restrict__ npb, const float* __restrict__ ew1,
    const float* __restrict__ eb1, const float* __restrict__ ew2,
    const float* __restrict__ eb2, const float* __restrict__ nw1,
    const float* __restrict__ nb1, const float* __restrict__ nw2,
    const float* __restrict__ nb2, const float* __restrict__ cpw,
    const float* __restrict__ cpb, float* __restrict__ out,
    float* ug0, float* ug1, float* vg0, float* vg1,
    int* idx, unsigned* bar) {
  __shared__ float xa[4 * HD];     // node features (persistent)
  __shared__ float um[4 * HD];     // my u/v rows  (persistent)
  __shared__ float scr[10240];     // 40 KB scratch
  float* part = scr;               // 4096
  float* rsp  = scr + 4096;        // 2048
  float* rs   = scr + 6144;        // 512
  float* ag   = scr + 6656;        // 512
  float* h1   = scr + 7168;        // 512
  float* xo   = scr + 7680;        // 512
  const int tid = threadIdx.x, b = blockIdx.x;
  const int cg = tid & 63, slot = tid >> 6;
  const int c0 = 2 * cg;
  const bool bird = b < 128;
  const int rside = (b & 127) * 4;     // row base within my side
  float a0, a1, a2, a3, a4, a5, a6, a7;

  // ---- sort rows 2b, 2b+1 (stable-descending rank = lax.top_k order) ----
  {
    float* srt = scr + 4096;           // 1024 floats
    const int h = tid >> 8, e = tid & 255;
    const int srow = 2 * b + h;
    srt[h * 512 + e]       = probs[srow * NC + e];
    srt[h * 512 + e + 256] = probs[srow * NC + e + 256];
    __syncthreads();
    const float v0 = srt[h * 512 + e], v1 = srt[h * 512 + e + 256];
    int r0_ = 0, r1_ = 0;
#pragma unroll 8
    for (int j4 = 0; j4 < 128; ++j4) {
      f4 sv = ((const f4*)(srt + h * 512))[j4];
      int j = 4 * j4;
      r0_ += (sv.x > v0) || (sv.x == v0 && (j + 0) < e);
      r0_ += (sv.y > v0) || (sv.y == v0 && (j + 1) < e);
      r0_ += (sv.z > v0) || (sv.z == v0 && (j + 2) < e);
      r0_ += (sv.w > v0) || (sv.w == v0 && (j + 3) < e);
      r1_ += (sv.x > v1) || (sv.x == v1 && (j + 0) < e + 256);
      r1_ += (sv.y > v1) || (sv.y == v1 && (j + 1) < e + 256);
      r1_ += (sv.z > v1) || (sv.z == v1 && (j + 2) < e + 256);
      r1_ += (sv.w > v1) || (sv.w == v1 && (j + 3) < e + 256);
    }
    idx[srow * NC + r0_] = e;
    idx[srow * NC + r1_] = e + 256;
    __syncthreads();
  }

  // ---- init: xa + um; publish u/v (parity 0) ----
  if (bird) {
    float* As = scr + 5120;            // 2048 floats: 4 probs rows
    ((f4*)As)[tid] = ((const f4*)(probs + rside * NC))[tid];
    __syncthreads();
    ZACC(); ACC8S(As, 512, npw, 64); WRPART();
    __syncthreads();
    { int r = tid >> 7, cc = tid & 127;
      xa[r * HD + cc] = PSUM(r, cc) + npb[cc]; }
    __syncthreads();
    ZACC(); ACC8S(xa, HD, ew1, 16); WRPART();
    __syncthreads();
    { int r = tid >> 7, cc = tid & 127;
      float uval = PSUM(r, cc) + eb1[cc];
      um[r * HD + cc] = uval;
      ug0[(rside + r) * HD + cc] = uval; }
  } else {
    { int r = tid >> 7, cc = tid & 127;
      xa[r * HD + cc] = npw[(rside + r) * HD + cc] + npb[cc]; }
    __syncthreads();
    ZACC(); ACC8S(xa, HD, ew1 + HD * HD, 16); WRPART();
    __syncthreads();
    { int r = tid >> 7, cc = tid & 127;
      float vval = PSUM(r, cc);
      um[r * HD + cc] = vval;
      vg0[(rside + r) * HD + cc] = vval; }
  }
  gbar(bar, 256);

  // ---- layer 0: read parity 0, write parity 1 ----
  phaseT(tid, cg, slot, c0, bird, rside, xa, um, part, rsp, rs, ag, h1, xo,
         bird ? vg0 : ug0, ew2, eb2, nw1, nb1, nw2, nb2,
         ew1 + 32768, eb1 + HD, bird ? ug1 : vg1);
  gbar(bar, 512);
  // ---- layer 1: read parity 1, write parity 0 (bird u stays LDS-local) ----
  phaseT(tid, cg, slot, c0, bird, rside, xa, um, part, rsp, rs, ag, h1, xo,
         bird ? vg1 : ug1, ew2 + 16384, eb2 + HD, nw1 + 32768, nb1 + HD,
         nw2 + 16384, nb2 + HD, ew1 + 65536, eb1 + 2 * HD,
         bird ? (float*)nullptr : vg0);
  gbar(bar, 768);
  if (!bird) return;

  // ---- layer 2 tail (bird only): R + aggr + MLP + gnn + combine + gather ----
  {
    const float* ew2l = ew2 + 32768; const float* eb2l = eb2 + 256;
    const float* nw1l = nw1 + 65536; const float* nb1l = nb1 + 256;
    const float* nw2l = nw2 + 32768; const float* nb2l = nb2 + 256;
    {  // R over vg0 with local u (um)
      const int s16 = tid >> 5, cg32 = tid & 31;
      const int row = s16 & 3, jq = s16 >> 2;
      f4 base = *(const f4*)&um[row * HD + 4 * cg32];
      const f4* O4 = (const f4*)vg0;
      f4 acc = make_float4(0.f, 0.f, 0.f, 0.f);
#pragma unroll 8
      for (int j = jq * 128; j < jq * 128 + 128; ++j) {
        f4 o = O4[j * 32 + cg32];
        acc.x += fmaxf(base.x + o.x, 0.f);
        acc.y += fmaxf(base.y + o.y, 0.f);
        acc.z += fmaxf(base.z + o.z, 0.f);
        acc.w += fmaxf(base.w + o.w, 0.f);
      }
      *(f4*)&rsp[s16 * HD + 4 * cg32] = acc;
    }
    __syncthreads();
    { int r = tid >> 7, cc = tid & 127;
      rs[r * HD + cc] = rsp[r * HD + cc] + rsp[(4 + r) * HD + cc] +
                        rsp[(8 + r) * HD + cc] + rsp[(12 + r) * HD + cc]; }
    __syncthreads();
    ZACC(); ACC8S(rs, HD, ew2l, 16); WRPART();
    __syncthreads();
    { int r = tid >> 7, cc = tid & 127;
      ag[r * HD + cc] = PSUM(r, cc) + 512.f * eb2l[cc]; }
    __syncthreads();
    ZACC(); ACC8S(xa, HD, nw1l, 16); ACC8S(ag, HD, nw1l + HD * HD, 16);
    WRPART();
    __syncthreads();
    { int r = tid >> 7, cc = tid & 127;
      h1[r * HD + cc] = fmaxf(PSUM(r, cc) + nb1l[cc], 0.f); }
    __syncthreads();
    ZACC(); ACC8S(h1, HD, nw2l, 16); WRPART();
    __syncthreads();
    { int r = tid >> 7, cc = tid & 127;
      xo[r * HD + cc] = PSUM(r, cc) + nb2l[cc]; }
    __syncthreads();
    // gnn scores + combine (thread = one output column, 4 rows)
    float* comb = scr + 4096;          // 2048 floats (rsp is dead)
    {
      float s0 = cpb[tid], s1 = s0, s2 = s0, s3 = s0;
#pragma unroll 8
      for (int k = 0; k < HD; ++k) {
        float w = cpw[k * NC + tid];
        s0 = fmaf(xo[k], w, s0);
        s1 = fmaf(xo[HD + k], w, s1);
        s2 = fmaf(xo[2 * HD + k], w, s2);
        s3 = fmaf(xo[3 * HD + k], w, s3);
      }
      comb[tid]        = s0 * probs[(rside + 0) * NC + tid];
      comb[512 + tid]  = s1 * probs[(rside + 1) * NC + tid];
      comb[1024 + tid] = s2 * probs[(rside + 2) * NC + tid];
      comb[1536 + tid] = s3 * probs[(rside + 3) * NC + tid];
    }
    __syncthreads();
#pragma unroll
    for (int i = 0; i < 4; ++i) {
      int ii = i * 512 + tid;
      int r = ii >> 9, j = ii & 511;
      int cc = idx[(rside + r) * NC + j];
      out[(rside + r) * NC + j] = 1.f - comb[r * 512 + cc];
    }
  }
}

extern "C" void kernel_launch(void* const* d_in, const int* in_sizes, int n_in,
                              void* d_out, int out_size, void* d_ws, size_t ws_size,
                              hipStream_t stream) {
  const float* probs = (const float*)d_in[0];
  const float* npw   = (const float*)d_in[1];
  const float* npb   = (const float*)d_in[2];
  const float* ew1   = (const float*)d_in[3];
  const float* eb1   = (const float*)d_in[4];
  const float* ew2   = (const float*)d_in[5];
  const float* eb2   = (const float*)d_in[6];
  const float* nw1   = (const float*)d_in[7];
  const float* nb1   = (const float*)d_in[8];
  const float* nw2   = (const float*)d_in[9];
  const float* nb2   = (const float*)d_in[10];
  const float* cpw   = (const float*)d_in[11];
  const float* cpb   = (const float*)d_in[12];

  unsigned* bar = (unsigned*)d_ws;
  float* base = (float*)d_ws + 1024;   // skip 4 KB barrier page
  float* ug0 = base;                   // 512*128 each
  float* ug1 = ug0 + NB * HD;
  float* vg0 = ug1 + NB * HD;
  float* vg1 = vg0 + NC * HD;
  int*  idx  = (int*)(vg1 + NC * HD);  // 512*512

  hipMemsetAsync(d_ws, 0, 4096, stream);   // reset grid barrier (graph-safe)
  mega<<<256, 512, 0, stream>>>(probs, npw, npb, ew1, eb1, ew2, eb2,
                                nw1, nb1, nw2, nb2, cpw, cpb,
                                (float*)d_out, ug0, ug1, vg0, vg1, idx, bar);
}

// Round 9
// 224.457 us; speedup vs baseline: 1.1878x; 1.1878x over previous
//
#include <hip/hip_runtime.h>

#define NB 512
#define NC 512
#define HD 128
typedef float2 f2;
typedef float4 f4;

// 8-slot k-split matmul over 4 source rows (stride SSTR) from LDS; W from L2.
// Each f2 weight load feeds 8 FMAs (4 rows x 2 cols); loads independent.
#define ACC8S(SB, SSTR, WP, KQ) { const f2* W2_ = (const f2*)(WP); const float* S_ = (SB); \
  _Pragma("unroll 8") for (int kk_ = 0; kk_ < (KQ); ++kk_) { \
    int k_ = slot * (KQ) + kk_; \
    f2 w_ = W2_[k_ * 64 + cg]; \
    float s0_ = S_[k_], s1_ = S_[(SSTR) + k_], s2_ = S_[2*(SSTR) + k_], s3_ = S_[3*(SSTR) + k_]; \
    a0 = fmaf(s0_, w_.x, a0); a1 = fmaf(s0_, w_.y, a1); \
    a2 = fmaf(s1_, w_.x, a2); a3 = fmaf(s1_, w_.y, a3); \
    a4 = fmaf(s2_, w_.x, a4); a5 = fmaf(s2_, w_.y, a5); \
    a6 = fmaf(s3_, w_.x, a6); a7 = fmaf(s3_, w_.y, a7); } }
#define ZACC() { a0=a1=a2=a3=a4=a5=a6=a7=0.f; }
#define WRPART() { float* P_ = part + slot * 512; \
  *(f2*)&P_[c0]     = make_float2(a0, a1); *(f2*)&P_[128 + c0] = make_float2(a2, a3); \
  *(f2*)&P_[256 + c0] = make_float2(a4, a5); *(f2*)&P_[384 + c0] = make_float2(a6, a7); }
#define PSUM(r_, cc_) (part[(r_)*128+(cc_)] + part[512+(r_)*128+(cc_)] + \
  part[1024+(r_)*128+(cc_)] + part[1536+(r_)*128+(cc_)] + part[2048+(r_)*128+(cc_)] + \
  part[2560+(r_)*128+(cc_)] + part[3072+(r_)*128+(cc_)] + part[3584+(r_)*128+(cc_)])

// Grid barrier, split into arrive/wait. KEY: the spin uses RELAXED loads (no
// per-poll L2 invalidate); exactly one acquire fence after the spin exits.
__device__ __forceinline__ void gbar_arrive(unsigned* bar) {
  __syncthreads();
  if (threadIdx.x == 0) {
    __threadfence();   // release: write back this XCD's L2 once
    __hip_atomic_fetch_add(bar, 1u, __ATOMIC_RELEASE, __HIP_MEMORY_SCOPE_AGENT);
  }
}
__device__ __forceinline__ void gbar_wait(unsigned* bar, unsigned target) {
  if (threadIdx.x == 0) {
    while (__hip_atomic_load(bar, __ATOMIC_RELAXED, __HIP_MEMORY_SCOPE_AGENT) < target)
      __builtin_amdgcn_s_sleep(4);
  }
  __syncthreads();
  __threadfence();     // acquire: invalidate caches ONCE after barrier
}

// One GNN layer for this block's 4 node rows. um = my-side u/v rows (LDS),
// other = opposite side's full endpoint array (global). Updates xa,um in LDS;
// writes my new endpoint rows to mine_out (if non-null) for the other side.
__device__ __forceinline__ void phaseT(
    int tid, int cg, int slot, int c0, bool bird, int rside,
    float* xa, float* um, float* part, float* rsp, float* rs, float* ag,
    float* h1, float* xo, const float* other,
    const float* ew2l, const float* eb2l, const float* nw1l, const float* nb1l,
    const float* nw2l, const float* nb2l, const float* ew1n, const float* eb1n,
    float* mine_out) {
  float a0, a1, a2, a3, a4, a5, a6, a7;
  {  // relu-sum: 16 slots = 4 rows x 4 j-quarters, f4 streams from L2
    const int s16 = tid >> 5, cg32 = tid & 31;
    const int row = s16 & 3, jq = s16 >> 2;
    f4 base = *(const f4*)&um[row * HD + 4 * cg32];
    const f4* O4 = (const f4*)other;
    f4 acc = make_float4(0.f, 0.f, 0.f, 0.f);
#pragma unroll 8
    for (int j = jq * 128; j < jq * 128 + 128; ++j) {
      f4 o = O4[j * 32 + cg32];
      acc.x += fmaxf(base.x + o.x, 0.f);
      acc.y += fmaxf(base.y + o.y, 0.f);
      acc.z += fmaxf(base.z + o.z, 0.f);
      acc.w += fmaxf(base.w + o.w, 0.f);
    }
    *(f4*)&rsp[s16 * HD + 4 * cg32] = acc;
  }
  __syncthreads();
  { int r = tid >> 7, cc = tid & 127;
    rs[r * HD + cc] = rsp[r * HD + cc] + rsp[(4 + r) * HD + cc] +
                      rsp[(8 + r) * HD + cc] + rsp[(12 + r) * HD + cc]; }
  __syncthreads();
  ZACC(); ACC8S(rs, HD, ew2l, 16); WRPART();                 // aggr
  __syncthreads();
  { int r = tid >> 7, cc = tid & 127;
    ag[r * HD + cc] = PSUM(r, cc) + 512.f * eb2l[cc]; }
  __syncthreads();
  ZACC(); ACC8S(xa, HD, nw1l, 16); ACC8S(ag, HD, nw1l + HD * HD, 16);  // mlp1
  WRPART();
  __syncthreads();
  { int r = tid >> 7, cc = tid & 127;
    h1[r * HD + cc] = fmaxf(PSUM(r, cc) + nb1l[cc], 0.f); }
  __syncthreads();
  ZACC(); ACC8S(h1, HD, nw2l, 16); WRPART();                 // mlp2
  __syncthreads();
  { int r = tid >> 7, cc = tid & 127;
    xo[r * HD + cc] = PSUM(r, cc) + nb2l[cc]; }
  __syncthreads();
  ZACC(); ACC8S(xo, HD, bird ? ew1n : ew1n + HD * HD, 16); WRPART();  // next u/v
  __syncthreads();
  { int r = tid >> 7, cc = tid & 127;
    float uval = PSUM(r, cc) + (bird ? eb1n[cc] : 0.f);
    um[r * HD + cc] = uval;
    if (mine_out) mine_out[(rside + r) * HD + cc] = uval;
    xa[r * HD + cc] = xo[r * HD + cc]; }
}

__global__ __launch_bounds__(512) void mega(
    const float* __restrict__ probs, const float* __restrict__ npw,
    const float* __restrict__ npb, const float* __restrict__ ew1,
    const float* __restrict__ eb1, const float* __restrict__ ew2,
    const float* __restrict__ eb2, const float* __restrict__ nw1,
    const float* __restrict__ nb1, const float* __restrict__ nw2,
    const float* __restrict__ nb2, const float* __restrict__ cpw,
    const float* __restrict__ cpb, float* __restrict__ out,
    float* ug0, float* ug1, float* vg0, float* vg1,
    int* idx, unsigned* bar) {
  __shared__ float xa[4 * HD];     // node features (persistent)
  __shared__ float um[4 * HD];     // my u/v rows  (persistent)
  __shared__ float scr[10240];     // 40 KB scratch
  float* part = scr;               // 4096
  float* rsp  = scr + 4096;        // 2048
  float* rs   = scr + 6144;        // 512
  float* ag   = scr + 6656;        // 512
  float* h1   = scr + 7168;        // 512
  float* xo   = scr + 7680;        // 512
  const int tid = threadIdx.x, b = blockIdx.x;
  const int cg = tid & 63, slot = tid >> 6;
  const int c0 = 2 * cg;
  const bool bird = b < 128;
  const int rside = (b & 127) * 4;     // row base within my side
  float a0, a1, a2, a3, a4, a5, a6, a7;

  // ---- sort rows 2b, 2b+1 (stable-descending rank = lax.top_k order) ----
  {
    float* srt = scr + 4096;           // 1024 floats
    const int h = tid >> 8, e = tid & 255;
    const int srow = 2 * b + h;
    srt[h * 512 + e]       = probs[srow * NC + e];
    srt[h * 512 + e + 256] = probs[srow * NC + e + 256];
    __syncthreads();
    const float v0 = srt[h * 512 + e], v1 = srt[h * 512 + e + 256];
    int r0_ = 0, r1_ = 0;
#pragma unroll 8
    for (int j4 = 0; j4 < 128; ++j4) {
      f4 sv = ((const f4*)(srt + h * 512))[j4];
      int j = 4 * j4;
      r0_ += (sv.x > v0) || (sv.x == v0 && (j + 0) < e);
      r0_ += (sv.y > v0) || (sv.y == v0 && (j + 1) < e);
      r0_ += (sv.z > v0) || (sv.z == v0 && (j + 2) < e);
      r0_ += (sv.w > v0) || (sv.w == v0 && (j + 3) < e);
      r1_ += (sv.x > v1) || (sv.x == v1 && (j + 0) < e + 256);
      r1_ += (sv.y > v1) || (sv.y == v1 && (j + 1) < e + 256);
      r1_ += (sv.z > v1) || (sv.z == v1 && (j + 2) < e + 256);
      r1_ += (sv.w > v1) || (sv.w == v1 && (j + 3) < e + 256);
    }
    idx[srow * NC + r0_] = e;
    idx[srow * NC + r1_] = e + 256;
    __syncthreads();
  }

  // ---- init: xa + um; publish u/v (parity 0) ----
  if (bird) {
    float* As = scr + 5120;            // 2048 floats: 4 probs rows
    ((f4*)As)[tid] = ((const f4*)(probs + rside * NC))[tid];
    __syncthreads();
    ZACC(); ACC8S(As, 512, npw, 64); WRPART();
    __syncthreads();
    { int r = tid >> 7, cc = tid & 127;
      xa[r * HD + cc] = PSUM(r, cc) + npb[cc]; }
    __syncthreads();
    ZACC(); ACC8S(xa, HD, ew1, 16); WRPART();
    __syncthreads();
    { int r = tid >> 7, cc = tid & 127;
      float uval = PSUM(r, cc) + eb1[cc];
      um[r * HD + cc] = uval;
      ug0[(rside + r) * HD + cc] = uval; }
  } else {
    { int r = tid >> 7, cc = tid & 127;
      xa[r * HD + cc] = npw[(rside + r) * HD + cc] + npb[cc]; }
    __syncthreads();
    ZACC(); ACC8S(xa, HD, ew1 + HD * HD, 16); WRPART();
    __syncthreads();
    { int r = tid >> 7, cc = tid & 127;
      float vval = PSUM(r, cc);
      um[r * HD + cc] = vval;
      vg0[(rside + r) * HD + cc] = vval; }
  }
  gbar_arrive(bar); gbar_wait(bar, 256);

  // ---- layer 0: read parity 0, write parity 1 ----
  phaseT(tid, cg, slot, c0, bird, rside, xa, um, part, rsp, rs, ag, h1, xo,
         bird ? vg0 : ug0, ew2, eb2, nw1, nb1, nw2, nb2,
         ew1 + 32768, eb1 + HD, bird ? ug1 : vg1);
  gbar_arrive(bar); gbar_wait(bar, 512);
  // ---- layer 1: read parity 1, write parity 0 (bird u stays LDS-local) ----
  phaseT(tid, cg, slot, c0, bird, rside, xa, um, part, rsp, rs, ag, h1, xo,
         bird ? vg1 : ug1, ew2 + 16384, eb2 + HD, nw1 + 32768, nb1 + HD,
         nw2 + 16384, nb2 + HD, ew1 + 65536, eb1 + 2 * HD,
         bird ? (float*)nullptr : vg0);
  gbar_arrive(bar);
  if (!bird) return;                   // colors only need to publish vg0
  gbar_wait(bar, 768);

  // ---- layer 2 tail (bird only): R + aggr + MLP + gnn + combine + gather ----
  {
    const float* ew2l = ew2 + 32768; const float* eb2l = eb2 + 256;
    const float* nw1l = nw1 + 65536; const float* nb1l = nb1 + 256;
    const float* nw2l = nw2 + 32768; const float* nb2l = nb2 + 256;
    {  // R over vg0 with local u (um)
      const int s16 = tid >> 5, cg32 = tid & 31;
      const int row = s16 & 3, jq = s16 >> 2;
      f4 base = *(const f4*)&um[row * HD + 4 * cg32];
      const f4* O4 = (const f4*)vg0;
      f4 acc = make_float4(0.f, 0.f, 0.f, 0.f);
#pragma unroll 8
      for (int j = jq * 128; j < jq * 128 + 128; ++j) {
        f4 o = O4[j * 32 + cg32];
        acc.x += fmaxf(base.x + o.x, 0.f);
        acc.y += fmaxf(base.y + o.y, 0.f);
        acc.z += fmaxf(base.z + o.z, 0.f);
        acc.w += fmaxf(base.w + o.w, 0.f);
      }
      *(f4*)&rsp[s16 * HD + 4 * cg32] = acc;
    }
    __syncthreads();
    { int r = tid >> 7, cc = tid & 127;
      rs[r * HD + cc] = rsp[r * HD + cc] + rsp[(4 + r) * HD + cc] +
                        rsp[(8 + r) * HD + cc] + rsp[(12 + r) * HD + cc]; }
    __syncthreads();
    ZACC(); ACC8S(rs, HD, ew2l, 16); WRPART();
    __syncthreads();
    { int r = tid >> 7, cc = tid & 127;
      ag[r * HD + cc] = PSUM(r, cc) + 512.f * eb2l[cc]; }
    __syncthreads();
    ZACC(); ACC8S(xa, HD, nw1l, 16); ACC8S(ag, HD, nw1l + HD * HD, 16);
    WRPART();
    __syncthreads();
    { int r = tid >> 7, cc = tid & 127;
      h1[r * HD + cc] = fmaxf(PSUM(r, cc) + nb1l[cc], 0.f); }
    __syncthreads();
    ZACC(); ACC8S(h1, HD, nw2l, 16); WRPART();
    __syncthreads();
    { int r = tid >> 7, cc = tid & 127;
      xo[r * HD + cc] = PSUM(r, cc) + nb2l[cc]; }
    __syncthreads();
    // gnn scores + combine (thread = one output column, 4 rows)
    float* comb = scr + 4096;          // 2048 floats (rsp is dead)
    {
      float s0 = cpb[tid], s1 = s0, s2 = s0, s3 = s0;
#pragma unroll 8
      for (int k = 0; k < HD; ++k) {
        float w = cpw[k * NC + tid];
        s0 = fmaf(xo[k], w, s0);
        s1 = fmaf(xo[HD + k], w, s1);
        s2 = fmaf(xo[2 * HD + k], w, s2);
        s3 = fmaf(xo[3 * HD + k], w, s3);
      }
      comb[tid]        = s0 * probs[(rside + 0) * NC + tid];
      comb[512 + tid]  = s1 * probs[(rside + 1) * NC + tid];
      comb[1024 + tid] = s2 * probs[(rside + 2) * NC + tid];
      comb[1536 + tid] = s3 * probs[(rside + 3) * NC + tid];
    }
    __syncthreads();
#pragma unroll
    for (int i = 0; i < 4; ++i) {
      int ii = i * 512 + tid;
      int r = ii >> 9, j = ii & 511;
      int cc = idx[(rside + r) * NC + j];
      out[(rside + r) * NC + j] = 1.f - comb[r * 512 + cc];
    }
  }
}

extern "C" void kernel_launch(void* const* d_in, const int* in_sizes, int n_in,
                              void* d_out, int out_size, void* d_ws, size_t ws_size,
                              hipStream_t stream) {
  const float* probs = (const float*)d_in[0];
  const float* npw   = (const float*)d_in[1];
  const float* npb   = (const float*)d_in[2];
  const float* ew1   = (const float*)d_in[3];
  const float* eb1   = (const float*)d_in[4];
  const float* ew2   = (const float*)d_in[5];
  const float* eb2   = (const float*)d_in[6];
  const float* nw1   = (const float*)d_in[7];
  const float* nb1   = (const float*)d_in[8];
  const float* nw2   = (const float*)d_in[9];
  const float* nb2   = (const float*)d_in[10];
  const float* cpw   = (const float*)d_in[11];
  const float* cpb   = (const float*)d_in[12];

  unsigned* bar = (unsigned*)d_ws;
  float* base = (float*)d_ws + 1024;   // skip 4 KB barrier page
  float* ug0 = base;                   // 512*128 each
  float* ug1 = ug0 + NB * HD;
  float* vg0 = ug1 + NB * HD;
  float* vg1 = vg0 + NC * HD;
  int*  idx  = (int*)(vg1 + NC * HD);  // 512*512

  hipMemsetAsync(d_ws, 0, 4096, stream);   // reset grid barrier (graph-safe)
  mega<<<256, 512, 0, stream>>>(probs, npw, npb, ew1, eb1, ew2, eb2,
                                nw1, nb1, nw2, nb2, cpw, cpb,
                                (float*)d_out, ug0, ug1, vg0, vg1, idx, bar);
}

// Round 10
// 117.620 us; speedup vs baseline: 2.2667x; 1.9083x over previous
//
#include <hip/hip_runtime.h>

#define NB 512
#define NC 512
#define HD 128
typedef float2 f2;
typedef float4 f4;

// 8-slot k-split matmul: thread = (cg: f2 output col, slot: k-eighth).
// Each weight load feeds 8 FMAs (4 rows x 2 cols); loads independent.
#define ACC8(SRC, WP, KQ) { const f2* W2_ = (const f2*)(WP); \
  _Pragma("unroll 16") for (int kk_ = 0; kk_ < (KQ); ++kk_) { \
    int k_ = slot * (KQ) + kk_; \
    f2 w_ = W2_[k_ * 64 + cg]; \
    float s0_ = SRC[0][k_], s1_ = SRC[1][k_], s2_ = SRC[2][k_], s3_ = SRC[3][k_]; \
    a0 = fmaf(s0_, w_.x, a0); a1 = fmaf(s0_, w_.y, a1); \
    a2 = fmaf(s1_, w_.x, a2); a3 = fmaf(s1_, w_.y, a3); \
    a4 = fmaf(s2_, w_.x, a4); a5 = fmaf(s2_, w_.y, a5); \
    a6 = fmaf(s3_, w_.x, a6); a7 = fmaf(s3_, w_.y, a7); } }
#define ZACC() { a0=a1=a2=a3=a4=a5=a6=a7=0.f; }
#define WRPART() { *(f2*)&part[slot][0][c0] = make_float2(a0, a1); \
  *(f2*)&part[slot][1][c0] = make_float2(a2, a3); \
  *(f2*)&part[slot][2][c0] = make_float2(a4, a5); \
  *(f2*)&part[slot][3][c0] = make_float2(a6, a7); }
#define PSUM(r_, cc_) (part[0][r_][cc_] + part[1][r_][cc_] + part[2][r_][cc_] + \
                       part[3][r_][cc_] + part[4][r_][cc_] + part[5][r_][cc_] + \
                       part[6][r_][cc_] + part[7][r_][cc_])

// ---------------------------------------------------------------------------
// k_pre: init only (sort moved to layer-0 dispatch). 256 blocks x 512 thr.
//  - blocks 0-127: bird rows 4b..4b+3: x0 = probs@npw+b, u0 = x0@ew1_top+eb1
//  - blocks 128-255: color rows: x0 = npw_row+b, v0 = x0@ew1_bot
// ---------------------------------------------------------------------------
__global__ __launch_bounds__(512) void k_pre(
    const float* __restrict__ probs, const float* __restrict__ npw,
    const float* __restrict__ npb, const float* __restrict__ ew1,
    const float* __restrict__ eb1, float* __restrict__ x0,
    float* __restrict__ u, float* __restrict__ v) {
  __shared__ float As[4][NC];        // 8 KB
  __shared__ float xs[4][HD];        // 2 KB
  __shared__ float part[8][4][HD];   // 16 KB
  const int tid = threadIdx.x, b = blockIdx.x;
  const int cg = tid & 63, slot = tid >> 6;
  const int c0 = 2 * cg;
  float a0, a1, a2, a3, a4, a5, a6, a7;

  if (b < 128) {                     // ---- bird ----
    const int r0 = b * 4;
    ((f4*)As)[tid] = ((const f4*)(probs + r0 * NC))[tid];
    __syncthreads();
    ZACC(); ACC8(As, npw, 64);       // k=512, 64 per slot
    WRPART();
    __syncthreads();
    { int r = tid >> 7, cc = tid & 127;
      float val = PSUM(r, cc) + npb[cc];
      xs[r][cc] = val;
      x0[(r0 + r) * HD + cc] = val; }
    __syncthreads();
    ZACC(); ACC8(xs, ew1, 16);       // u = xs @ ew1_top + eb1
    WRPART();
    __syncthreads();
    { int r = tid >> 7, cc = tid & 127;
      u[(r0 + r) * HD + cc] = PSUM(r, cc) + eb1[cc]; }
  } else {                           // ---- color ----
    const int cr0 = (b - 128) * 4;
    { int r = tid >> 7, cc = tid & 127;
      float val = npw[(cr0 + r) * HD + cc] + npb[cc];
      xs[r][cc] = val;
      x0[(NB + cr0 + r) * HD + cc] = val; }
    __syncthreads();
    ZACC(); ACC8(xs, ew1 + HD * HD, 16);   // v = xs @ ew1_bottom
    WRPART();
    __syncthreads();
    { int r = tid >> 7, cc = tid & 127;
      v[(cr0 + r) * HD + cc] = PSUM(r, cc); }
  }
}

// ---------------------------------------------------------------------------
// k_RSlayer: fused relu-sum + layer. Block b<256 owns node rows 4b..4b+3
// (bird for b<128, color for 128<=b<256). RS never leaves LDS.
// Blocks 256-383 (layer-0 dispatch only): stable-descending argsort of
// probs rows 4(b-256)..+3 (lax.top_k order) -> idx. idx is first read by
// k_last, two dispatches later (no race).
// ---------------------------------------------------------------------------
__global__ __launch_bounds__(512) void k_RSlayer(
    const float* __restrict__ xin, const float* __restrict__ uin,
    const float* __restrict__ vin,
    const float* __restrict__ ew2l, const float* __restrict__ eb2l,
    const float* __restrict__ nw1l, const float* __restrict__ nb1l,
    const float* __restrict__ nw2l, const float* __restrict__ nb2l,
    const float* __restrict__ ew1n, const float* __restrict__ eb1n,
    float* __restrict__ xout, float* __restrict__ uout, float* __restrict__ vout,
    const float* __restrict__ probs, int* __restrict__ idx) {
  __shared__ float rsp[16][HD];      // 8 KB RS partials / sort rows
  __shared__ float xa[4][HD], rs[4][HD], ag[4][HD], h1[4][HD], xo[4][HD];
  __shared__ float part[8][4][HD];   // 16 KB
  const int tid = threadIdx.x, b = blockIdx.x;

  if (b >= 256) {                    // ---- sort blocks (layer-0 only) ----
    float* srt = &rsp[0][0];         // 2048 floats = 4 rows
    const int r0 = (b - 256) * 4;
    for (int i = tid; i < 4 * NC; i += 512) srt[i] = probs[r0 * NC + i];
    __syncthreads();
#pragma unroll
    for (int r = 0; r < 4; ++r) {
      const float* row = srt + r * NC;
      const float myv = row[tid];
      int rank = 0;
#pragma unroll 16
      for (int j4 = 0; j4 < 128; ++j4) {
        f4 sv = ((const f4*)row)[j4];
        int j = 4 * j4;
        rank += (sv.x > myv) || (sv.x == myv && (j + 0) < tid);
        rank += (sv.y > myv) || (sv.y == myv && (j + 1) < tid);
        rank += (sv.z > myv) || (sv.z == myv && (j + 2) < tid);
        rank += (sv.w > myv) || (sv.w == myv && (j + 3) < tid);
      }
      idx[(r0 + r) * NC + rank] = tid;
    }
    return;
  }

  const int cg = tid & 63, slot = tid >> 6;
  const int c0 = 2 * cg;
  const int nr0 = b * 4;
  const bool bird = b < 128;
  const int r0s = (b & 127) * 4;
  float a0, a1, a2, a3, a4, a5, a6, a7;

  if (tid < 256) ((f2*)xa)[tid] = ((const f2*)(xin + nr0 * HD))[tid];

  // ---- RS phase: 16 slots = 4 rows x 4 j-quarters, f4 loads from L2 ----
  {
    const float* mine  = bird ? uin : vin;
    const float* other = bird ? vin : uin;
    const int s16 = tid >> 5, cg32 = tid & 31;
    const int row = s16 & 3, jq = s16 >> 2;
    f4 base = *(const f4*)&mine[(r0s + row) * HD + 4 * cg32];
    const f4* O4 = (const f4*)other;
    f4 acc = make_float4(0.f, 0.f, 0.f, 0.f);
#pragma unroll 16
    for (int j = jq * 128; j < jq * 128 + 128; ++j) {
      f4 o = O4[j * 32 + cg32];
      acc.x += fmaxf(base.x + o.x, 0.f);
      acc.y += fmaxf(base.y + o.y, 0.f);
      acc.z += fmaxf(base.z + o.z, 0.f);
      acc.w += fmaxf(base.w + o.w, 0.f);
    }
    *(f4*)&rsp[s16][4 * cg32] = acc;
  }
  __syncthreads();
  { int r = tid >> 7, cc = tid & 127;
    rs[r][cc] = rsp[r][cc] + rsp[4 + r][cc] + rsp[8 + r][cc] + rsp[12 + r][cc]; }
  __syncthreads();

  ZACC(); ACC8(rs, ew2l, 16);                    // phase 1: aggr
  WRPART();
  __syncthreads();
  { int r = tid >> 7, cc = tid & 127;
    ag[r][cc] = PSUM(r, cc) + 512.f * eb2l[cc]; }
  __syncthreads();

  ZACC();                                        // phase 2: node MLP layer 1
  ACC8(xa, nw1l, 16);
  ACC8(ag, nw1l + HD * HD, 16);
  WRPART();
  __syncthreads();
  { int r = tid >> 7, cc = tid & 127;
    h1[r][cc] = fmaxf(PSUM(r, cc) + nb1l[cc], 0.f); }
  __syncthreads();

  ZACC(); ACC8(h1, nw2l, 16);                    // phase 3: node MLP layer 2
  WRPART();
  __syncthreads();
  { int r = tid >> 7, cc = tid & 127;
    float val = PSUM(r, cc) + nb2l[cc];
    xo[r][cc] = val;
    xout[(nr0 + r) * HD + cc] = val; }
  __syncthreads();

  ZACC(); ACC8(xo, (bird ? ew1n : ew1n + HD * HD), 16);   // phase 4: next u/v
  WRPART();
  __syncthreads();
  { int r = tid >> 7, cc = tid & 127;
    float val = PSUM(r, cc) + (bird ? eb1n[cc] : 0.f);
    if (bird) uout[(nr0 + r) * HD + cc] = val;
    else      vout[(nr0 - NB + r) * HD + cc] = val; }
}

// ---------------------------------------------------------------------------
// k_last: 128 blocks x 4 bird rows. R-sum + aggr + node MLP + gnn scores +
// combine with probs + idx-gather -> d_out. (S and color x' are dead.)
// ---------------------------------------------------------------------------
__global__ __launch_bounds__(512) void k_last(
    const float* __restrict__ xin, const float* __restrict__ uin,
    const float* __restrict__ vin,
    const float* __restrict__ ew2l, const float* __restrict__ eb2l,
    const float* __restrict__ nw1l, const float* __restrict__ nb1l,
    const float* __restrict__ nw2l, const float* __restrict__ nb2l,
    const float* __restrict__ cpw, const float* __restrict__ cpb,
    const float* __restrict__ probs, const int* __restrict__ idx,
    float* __restrict__ out) {
  __shared__ float rsp[16][HD];      // 8 KB
  __shared__ float xa[4][HD], rs[4][HD], ag[4][HD], h1[4][HD], xo[4][HD];
  __shared__ float part[8][4][HD];   // 16 KB
  __shared__ float comb[4][NC];      // 8 KB
  const int tid = threadIdx.x, b = blockIdx.x;
  const int cg = tid & 63, slot = tid >> 6;
  const int c0 = 2 * cg;
  const int nr0 = b * 4;
  float a0, a1, a2, a3, a4, a5, a6, a7;

  if (tid < 256) ((f2*)xa)[tid] = ((const f2*)(xin + nr0 * HD))[tid];

  {  // ---- R phase over v ----
    const int s16 = tid >> 5, cg32 = tid & 31;
    const int row = s16 & 3, jq = s16 >> 2;
    f4 base = *(const f4*)&uin[(nr0 + row) * HD + 4 * cg32];
    const f4* O4 = (const f4*)vin;
    f4 acc = make_float4(0.f, 0.f, 0.f, 0.f);
#pragma unroll 16
    for (int j = jq * 128; j < jq * 128 + 128; ++j) {
      f4 o = O4[j * 32 + cg32];
      acc.x += fmaxf(base.x + o.x, 0.f);
      acc.y += fmaxf(base.y + o.y, 0.f);
      acc.z += fmaxf(base.z + o.z, 0.f);
      acc.w += fmaxf(base.w + o.w, 0.f);
    }
    *(f4*)&rsp[s16][4 * cg32] = acc;
  }
  __syncthreads();
  { int r = tid >> 7, cc = tid & 127;
    rs[r][cc] = rsp[r][cc] + rsp[4 + r][cc] + rsp[8 + r][cc] + rsp[12 + r][cc]; }
  __syncthreads();

  ZACC(); ACC8(rs, ew2l, 16);
  WRPART();
  __syncthreads();
  { int r = tid >> 7, cc = tid & 127;
    ag[r][cc] = PSUM(r, cc) + 512.f * eb2l[cc]; }
  __syncthreads();

  ZACC();
  ACC8(xa, nw1l, 16);
  ACC8(ag, nw1l + HD * HD, 16);
  WRPART();
  __syncthreads();
  { int r = tid >> 7, cc = tid & 127;
    h1[r][cc] = fmaxf(PSUM(r, cc) + nb1l[cc], 0.f); }
  __syncthreads();

  ZACC(); ACC8(h1, nw2l, 16);
  WRPART();
  __syncthreads();
  { int r = tid >> 7, cc = tid & 127;
    xo[r][cc] = PSUM(r, cc) + nb2l[cc]; }
  __syncthreads();

  // ---- gnn scores + combine: thread = one output column, 4 rows ----
  {
    const int c = tid;
    float s0 = cpb[c], s1 = s0, s2 = s0, s3 = s0;
#pragma unroll 16
    for (int k = 0; k < HD; ++k) {
      float w = cpw[k * NC + c];
      s0 = fmaf(xo[0][k], w, s0);
      s1 = fmaf(xo[1][k], w, s1);
      s2 = fmaf(xo[2][k], w, s2);
      s3 = fmaf(xo[3][k], w, s3);
    }
    comb[0][c] = s0 * probs[(nr0 + 0) * NC + c];
    comb[1][c] = s1 * probs[(nr0 + 1) * NC + c];
    comb[2][c] = s2 * probs[(nr0 + 2) * NC + c];
    comb[3][c] = s3 * probs[(nr0 + 3) * NC + c];
  }
  __syncthreads();
#pragma unroll
  for (int i = 0; i < 4; ++i) {
    int ii = i * 512 + tid;
    int r = ii >> 9, j = ii & 511;
    int cc = idx[(nr0 + r) * NC + j];
    out[(nr0 + r) * NC + j] = 1.f - comb[r][cc];
  }
}

extern "C" void kernel_launch(void* const* d_in, const int* in_sizes, int n_in,
                              void* d_out, int out_size, void* d_ws, size_t ws_size,
                              hipStream_t stream) {
  const float* probs = (const float*)d_in[0];
  const float* npw   = (const float*)d_in[1];
  const float* npb   = (const float*)d_in[2];
  const float* ew1   = (const float*)d_in[3];
  const float* eb1   = (const float*)d_in[4];
  const float* ew2   = (const float*)d_in[5];
  const float* eb2   = (const float*)d_in[6];
  const float* nw1   = (const float*)d_in[7];
  const float* nb1   = (const float*)d_in[8];
  const float* nw2   = (const float*)d_in[9];
  const float* nb2   = (const float*)d_in[10];
  const float* cpw   = (const float*)d_in[11];
  const float* cpb   = (const float*)d_in[12];
  float* out = (float*)d_out;

  float* x0 = (float*)d_ws;          // 1024*128
  float* x1 = x0 + 1024 * HD;
  float* ua = x1 + 1024 * HD;        // 512*128 each
  float* va = ua + NB * HD;
  float* ub = va + NC * HD;
  float* vb = ub + NB * HD;
  int*  idx = (int*)(vb + NC * HD);  // 512*512

  k_pre    <<<256, 512, 0, stream>>>(probs, npw, npb, ew1, eb1, x0, ua, va);
  // layer 0 (+128 sort blocks): x0 -> x1, (ua,va) -> (ub,vb)
  k_RSlayer<<<384, 512, 0, stream>>>(x0, ua, va, ew2, eb2, nw1, nb1, nw2, nb2,
                                     ew1 + 32768, eb1 + HD, x1, ub, vb,
                                     probs, idx);
  // layer 1: x1 -> x0, (ub,vb) -> (ua,va)
  k_RSlayer<<<256, 512, 0, stream>>>(x1, ub, vb, ew2 + 16384, eb2 + HD,
                                     nw1 + 32768, nb1 + HD, nw2 + 16384, nb2 + HD,
                                     ew1 + 65536, eb1 + 2 * HD, x0, ua, va,
                                     probs, idx);
  // layer 2 (bird only) fused through to d_out
  k_last   <<<128, 512, 0, stream>>>(x0, ua, va, ew2 + 32768, eb2 + 2 * HD,
                                     nw1 + 65536, nb1 + 2 * HD,
                                     nw2 + 32768, nb2 + 2 * HD,
                                     cpw, cpb, probs, idx, out);
}